// Round 1
// baseline (104.834 us; speedup 1.0000x reference)
//
#include <hip/hip_runtime.h>

#define N 384
#define D 128
#define TLMARGIN 0.2f
#define BLK 256

// One block per anchor a:
//  - stage feat[a] (128 f32) and labels (384 i32) in LDS
//  - compute d2[a][j] = sum_d (feat[a][d]-feat[j][d])^2 for all j (threads stride j)
//  - accumulate sum over valid (p,n): relu(d2[p] - d2[n] + margin)
//  - block-reduce, atomicAdd partial sum and triplet count into ws[0], ws[1]
__global__ __launch_bounds__(BLK) void triplet_kernel(const float* __restrict__ feat,
                                                      const int* __restrict__ y,
                                                      float* __restrict__ ws) {
    __shared__ float sfa[D];
    __shared__ float sd2[N];
    __shared__ int   sy[N];
    __shared__ float sred[BLK];

    const int a = blockIdx.x;
    const int t = threadIdx.x;

    if (t < D) sfa[t] = feat[a * D + t];
    for (int j = t; j < N; j += BLK) sy[j] = y[j];
    __syncthreads();

    // d2 row for anchor a (direct squared-diff: nonneg by construction)
    for (int j = t; j < N; j += BLK) {
        const float* fj = feat + j * D;
        float s = 0.f;
        #pragma unroll 8
        for (int d = 0; d < D; ++d) {
            float diff = sfa[d] - fj[d];
            s = fmaf(diff, diff, s);
        }
        sd2[j] = s;
    }
    __syncthreads();

    const int ya = sy[a];

    // triplet accumulation: loop positives serially, negatives across threads
    float acc = 0.f;
    for (int p = 0; p < N; ++p) {
        if (p == a || sy[p] != ya) continue;
        const float dp = sd2[p] + TLMARGIN;
        for (int n = t; n < N; n += BLK) {
            // invalid negatives (same label) contribute 0 via mask
            float v = dp - sd2[n];
            v = (v > 0.f) ? v : 0.f;
            acc += (sy[n] != ya) ? v : 0.f;
        }
    }

    sred[t] = acc;
    __syncthreads();
    #pragma unroll
    for (int s = BLK / 2; s > 0; s >>= 1) {
        if (t < s) sred[t] += sred[t + s];
        __syncthreads();
    }

    if (t == 0) {
        int same = 0;
        for (int j = 0; j < N; ++j) same += (sy[j] == ya) ? 1 : 0;
        const int npos = same - 1;       // exclude self
        const int nneg = N - same;       // different label
        atomicAdd(&ws[0], sred[0]);
        atomicAdd(&ws[1], (float)(npos * nneg));
    }
}

__global__ void finalize_kernel(const float* __restrict__ ws, float* __restrict__ out) {
    out[0] = ws[0] / ws[1];
}

extern "C" void kernel_launch(void* const* d_in, const int* in_sizes, int n_in,
                              void* d_out, int out_size, void* d_ws, size_t ws_size,
                              hipStream_t stream) {
    const float* feat = (const float*)d_in[0];
    // d_in[1] = logits (unused by the reference)
    const int* y = (const int*)d_in[2];
    float* ws = (float*)d_ws;
    float* out = (float*)d_out;

    hipMemsetAsync(ws, 0, 2 * sizeof(float), stream);
    triplet_kernel<<<N, BLK, 0, stream>>>(feat, y, ws);
    finalize_kernel<<<1, 1, 0, stream>>>(ws, out);
}

// Round 2
// 79.214 us; speedup vs baseline: 1.3234x; 1.3234x over previous
//
#include <hip/hip_runtime.h>

#define N 384
#define D 128
#define TLMARGIN 0.2f

// Pass 1: featT[d][j] = feat[j][d] so the main kernel's per-lane row reads
// become coalesced column reads. 384x128 floats = 196 KB, lives in d_ws.
__global__ __launch_bounds__(256) void transpose_kernel(const float* __restrict__ feat,
                                                        float* __restrict__ featT) {
    __shared__ float tile[32][33];   // +1 pad: conflict-free both phases
    const int jx = threadIdx.x;      // 0..31
    const int ty = threadIdx.y;      // 0..7
    const int j0 = blockIdx.x * 32;  // 12 j-tiles
    const int d0 = blockIdx.y * 32;  // 4 d-tiles
    #pragma unroll
    for (int k = 0; k < 4; ++k) {
        int jj = ty + 8 * k;
        tile[jj][jx] = feat[(j0 + jj) * D + d0 + jx];   // coalesced over d
    }
    __syncthreads();
    #pragma unroll
    for (int k = 0; k < 4; ++k) {
        int dd = ty + 8 * k;
        featT[(d0 + dd) * N + j0 + jx] = tile[jx][dd];  // coalesced over j
    }
}

// Pass 2: one block per anchor, 384 threads (thread t == candidate j/n).
//  - d2 row from coalesced featT reads (4 independent fma chains)
//  - positive list built once via LDS atomics (~12 entries, C=32 classes)
//  - each negative thread sums relu(d2[p]+m-d2[n]) over the positive list
//  - shfl reduce -> block atomicAdd -> last block writes out = total/count
__global__ __launch_bounds__(N) void triplet_main(const float* __restrict__ feat,
                                                  const float* __restrict__ featT,
                                                  const int* __restrict__ y,
                                                  float* __restrict__ ws,
                                                  float* __restrict__ out) {
    __shared__ float sfa[D];
    __shared__ float sd2[N];
    __shared__ int   plist[96];
    __shared__ int   pcount;
    __shared__ float swsum[N / 64];

    const int a = blockIdx.x;
    const int t = threadIdx.x;
    const int ya = y[a];      // uniform scalar load
    const int yt = y[t];      // coalesced

    if (t < D) sfa[t] = feat[a * D + t];
    if (t == 0) pcount = 0;
    __syncthreads();

    // d2[a][t] = sum_d (feat[a][d] - feat[t][d])^2, reading featT coalesced
    const float* ft = featT + t;
    float s0 = 0.f, s1 = 0.f, s2 = 0.f, s3 = 0.f;
    #pragma unroll 8
    for (int d = 0; d < D; d += 4) {
        float x0 = sfa[d + 0] - ft[(d + 0) * N];
        float x1 = sfa[d + 1] - ft[(d + 1) * N];
        float x2 = sfa[d + 2] - ft[(d + 2) * N];
        float x3 = sfa[d + 3] - ft[(d + 3) * N];
        s0 = fmaf(x0, x0, s0);
        s1 = fmaf(x1, x1, s1);
        s2 = fmaf(x2, x2, s2);
        s3 = fmaf(x3, x3, s3);
    }
    sd2[t] = (s0 + s1) + (s2 + s3);

    if (t != a && yt == ya) {
        int idx = atomicAdd(&pcount, 1);
        plist[idx] = t;
    }
    __syncthreads();

    const int np = pcount;          // uniform after barrier
    float acc = 0.f;
    if (yt != ya) {                 // this thread is a valid negative n=t
        const float dn = sd2[t] - TLMARGIN;
        for (int i = 0; i < np; ++i) {
            float v = sd2[plist[i]] - dn;   // d2[p] + margin - d2[n]
            acc += fmaxf(v, 0.f);
        }
    }

    // reduce 384 threads: 6-step shfl within each wave, then 6 partials
    #pragma unroll
    for (int off = 32; off > 0; off >>= 1)
        acc += __shfl_down(acc, off);
    if ((t & 63) == 0) swsum[t >> 6] = acc;
    __syncthreads();

    if (t == 0) {
        float bs = 0.f;
        #pragma unroll
        for (int w = 0; w < N / 64; ++w) bs += swsum[w];
        const int nneg = N - np - 1;
        atomicAdd(&ws[0], bs);
        atomicAdd(&ws[1], (float)(np * nneg));
        __threadfence();
        unsigned int old = atomicAdd((unsigned int*)&ws[2], 1u);
        if (old == (unsigned int)(gridDim.x - 1)) {
            // all block contributions are ordered before the counter bump;
            // read through atomics to stay at the device coherence point
            float tot = atomicAdd(&ws[0], 0.f);
            float cnt = atomicAdd(&ws[1], 0.f);
            out[0] = tot / cnt;
        }
    }
}

extern "C" void kernel_launch(void* const* d_in, const int* in_sizes, int n_in,
                              void* d_out, int out_size, void* d_ws, size_t ws_size,
                              hipStream_t stream) {
    const float* feat = (const float*)d_in[0];
    // d_in[1] = logits (unused by the reference)
    const int* y = (const int*)d_in[2];
    float* ws = (float*)d_ws;            // [0]=total [1]=count [2]=done ctr
    float* featT = ws + 16;              // 64 B offset, 16 B aligned
    float* out = (float*)d_out;

    hipMemsetAsync(d_ws, 0, 16, stream);
    transpose_kernel<<<dim3(12, 4), dim3(32, 8), 0, stream>>>(feat, featT);
    triplet_main<<<N, N, 0, stream>>>(feat, featT, y, ws, out);
}

// Round 3
// 77.883 us; speedup vs baseline: 1.3460x; 1.0171x over previous
//
#include <hip/hip_runtime.h>

#define N 384
#define D 128
#define TLMARGIN 0.2f
#define TS 32          // d2 tile size

// ws layout: ws[0]=total  ws[1]=count  ws[2]=done-counter  ws[3]=pad
//            ws+64 .. : d2 matrix [N][N] floats (576 KB)

// Kernel 1: d2[i][j] = sum_d (feat[i][d]-feat[j][d])^2, LDS-tiled 32x32.
// Block (0,0) also zero-inits the accumulators (visible to kernel 2 via
// stream ordering). Each block reads 2 x 16 KB coalesced; total 4.6 MB.
__global__ __launch_bounds__(256) void d2_kernel(const float* __restrict__ feat,
                                                 float* __restrict__ ws) {
    __shared__ float As[TS][D + 1];   // +1 pad: conflict-free LDS
    __shared__ float Bs[TS][D + 1];

    const int t = threadIdx.x;
    const int i0 = blockIdx.x * TS;
    const int j0 = blockIdx.y * TS;

    if (blockIdx.x == 0 && blockIdx.y == 0 && t < 4) ws[t] = 0.f;

    // load 32x128 A-tile and B-tile, coalesced (16 floats per thread each)
    #pragma unroll
    for (int k = 0; k < 16; ++k) {
        const int f = t + 256 * k;
        const int r = f >> 7, c = f & 127;
        As[r][c] = feat[(i0 + r) * D + c];
        Bs[r][c] = feat[(j0 + r) * D + c];
    }
    __syncthreads();

    // 256 threads -> each computes 4 outputs: rows ti0..ti0+3, col tj
    const int tj = t & 31;
    const int ti0 = (t >> 5) << 2;
    float a0 = 0.f, a1 = 0.f, a2 = 0.f, a3 = 0.f;
    #pragma unroll 4
    for (int d = 0; d < D; ++d) {
        const float b = Bs[tj][d];            // 32 distinct banks
        const float x0 = As[ti0 + 0][d] - b;  // broadcast reads
        const float x1 = As[ti0 + 1][d] - b;
        const float x2 = As[ti0 + 2][d] - b;
        const float x3 = As[ti0 + 3][d] - b;
        a0 = fmaf(x0, x0, a0);
        a1 = fmaf(x1, x1, a1);
        a2 = fmaf(x2, x2, a2);
        a3 = fmaf(x3, x3, a3);
    }

    float* d2m = ws + 64;
    d2m[(i0 + ti0 + 0) * N + j0 + tj] = a0;
    d2m[(i0 + ti0 + 1) * N + j0 + tj] = a1;
    d2m[(i0 + ti0 + 2) * N + j0 + tj] = a2;
    d2m[(i0 + ti0 + 3) * N + j0 + tj] = a3;
}

// Kernel 2: one block per anchor, thread t == candidate j/n.
// Reads its 1.5 KB d2 row coalesced; positive list via LDS atomics;
// shfl reduce; device atomics; last block writes out = total/count.
__global__ __launch_bounds__(N) void triplet_kernel(const int* __restrict__ y,
                                                    float* __restrict__ ws,
                                                    float* __restrict__ out) {
    __shared__ float sd2[N];
    __shared__ int   plist[96];
    __shared__ int   pcount;
    __shared__ float swsum[N / 64];

    const int a = blockIdx.x;
    const int t = threadIdx.x;
    const float* d2m = ws + 64;

    const int ya = y[a];
    const int yt = y[t];
    sd2[t] = d2m[a * N + t];
    if (t == 0) pcount = 0;
    __syncthreads();

    if (t != a && yt == ya) {
        int idx = atomicAdd(&pcount, 1);
        plist[idx] = t;
    }
    __syncthreads();

    const int np = pcount;          // uniform after barrier
    float acc = 0.f;
    if (yt != ya) {                 // this thread is a valid negative n=t
        const float dn = sd2[t] - TLMARGIN;
        for (int i = 0; i < np; ++i) {
            float v = sd2[plist[i]] - dn;   // d2[p] + margin - d2[n]
            acc += fmaxf(v, 0.f);
        }
    }

    #pragma unroll
    for (int off = 32; off > 0; off >>= 1)
        acc += __shfl_down(acc, off);
    if ((t & 63) == 0) swsum[t >> 6] = acc;
    __syncthreads();

    if (t == 0) {
        float bs = 0.f;
        #pragma unroll
        for (int w = 0; w < N / 64; ++w) bs += swsum[w];
        const int nneg = N - 1 - np;
        atomicAdd(&ws[0], bs);
        atomicAdd(&ws[1], (float)(np * nneg));
        __threadfence();
        unsigned int old = atomicAdd((unsigned int*)&ws[2], 1u);
        if (old == (unsigned int)(gridDim.x - 1)) {
            float tot = atomicAdd(&ws[0], 0.f);
            float cnt = atomicAdd(&ws[1], 0.f);
            out[0] = tot / cnt;
        }
    }
}

extern "C" void kernel_launch(void* const* d_in, const int* in_sizes, int n_in,
                              void* d_out, int out_size, void* d_ws, size_t ws_size,
                              hipStream_t stream) {
    const float* feat = (const float*)d_in[0];
    // d_in[1] = logits (unused by the reference)
    const int* y = (const int*)d_in[2];
    float* ws = (float*)d_ws;
    float* out = (float*)d_out;

    d2_kernel<<<dim3(N / TS, N / TS), 256, 0, stream>>>(feat, ws);
    triplet_kernel<<<N, N, 0, stream>>>(y, ws, out);
}